// Round 8
// baseline (1669.977 us; speedup 1.0000x reference)
//
#include <hip/hip_runtime.h>
#include <hip/hip_bf16.h>
#include <math.h>

#define BB 4
#define SEQ 512
#define TGT 256
#define DM 512
#define FFD 2048
#define NH 8
#define HD 64
#define NL 6

typedef unsigned short u16;
typedef __attribute__((ext_vector_type(4))) float f4;
typedef __attribute__((ext_vector_type(4))) unsigned short us4;
typedef __attribute__((ext_vector_type(8))) unsigned short us8;
typedef __attribute__((ext_vector_type(8))) short s8;

__device__ inline u16 f2b(float f) {
    __hip_bfloat16 h = __float2bfloat16(f);
    return *reinterpret_cast<u16*>(&h);
}
__device__ inline float b2f(u16 u) {
    unsigned int x = ((unsigned int)u) << 16;
    float f;
    __builtin_memcpy(&f, &x, 4);
    return f;
}
__device__ inline us4 cvt4(f4 v) {
    us4 u;
    u.x = f2b(v.x); u.y = f2b(v.y); u.z = f2b(v.z); u.w = f2b(v.w);
    return u;
}

// apply layernorm to 8 bf16 values on read: (y-mean)*rstd*g[k]+b[k]
__device__ inline us8 lnx8(us8 y, float mean, float rstd,
                           const float* __restrict__ g, const float* __restrict__ b) {
    us8 o;
#pragma unroll
    for (int e = 0; e < 8; e++)
        o[e] = f2b((b2f(y[e]) - mean) * rstd * g[e] + b[e]);
    return o;
}

// ---------------- zero the LN stats region ----------------
__global__ __launch_bounds__(256) void zero_k(float* __restrict__ p, int n)
{
    int i = blockIdx.x * 256 + threadIdx.x;
    if (i < n) p[i] = 0.f;
}

// ---------------- batched fp32 -> bf16 cast ----------------
// Pinned at ~75us / 2.4 TB/s across three access-pattern variants. Leave it.
struct CastSegs {
    const float* src[24];
    u16* dst[24];
    int cum[25];   // cumulative n4 (f4 groups)
    int nseg;
};

__global__ __launch_bounds__(256) void castseg_k(CastSegs cs)
{
    const int g0 = blockIdx.x << 11;           // first f4-group of this block
    int s = 0;
    while (g0 >= cs.cum[s + 1]) s++;           // block-uniform search
    const f4* __restrict__ sp = (const f4*)cs.src[s];
    us4* __restrict__ dp = (us4*)cs.dst[s];
    const int base = g0 - cs.cum[s] + (int)threadIdx.x;

    f4 v[8];
#pragma unroll
    for (int k = 0; k < 8; k++) v[k] = sp[base + (k << 8)];
#pragma unroll
    for (int k = 0; k < 8; k++) dp[base + (k << 8)] = cvt4(v[k]);
}

// ---------------- stack decoder cross-attn KV biases: [6][1024] fp32 ----------------
__global__ void kvbias_k(const float* __restrict__ dec_ca_b, float* __restrict__ out)
{
    int idx = blockIdx.x * blockDim.x + threadIdx.x;
    if (idx >= NL * 2 * DM) return;
    int layer = idx >> 10, j = idx & 1023;
    out[idx] = dec_ca_b[layer * 3 * DM + DM + j];
}

// ============ MFMA GEMM, bf16, BMxBN tile, BK=64, double-buffered LDS ============
// PE: 0 none, 1 encoder sinusoidal pe, 2 decoder pe row 0
// KVMAP: remap B row n -> layer*3*DM + DM + (n&1023) (kvall GEMM).
// R8 LN fusion (removes all 30 ln_k dispatches, ~5us each incl gaps):
//   LNA   : A is a raw pre-LN tensor; normalize during LDS staging using
//           producer-accumulated row stats (lnst_in) + g_in/b_in.
//   LNRES : resid is a raw pre-LN tensor; normalize at the epilogue resid add.
//   LNOUT : this GEMM produces a pre-LN tensor y = A@W^T+bias(+resid); epilogue
//           accumulates per-row sum/sumsq into lnst_out via atomicAdd
//           (16-lane shfl column-reduce first; stats complete when the next
//           kernel in stream order reads them). LNRES/LNOUT only at 32x32.
template <int RELU, int OUTF32, int BM, int BN, int PE, int KVMAP,
          int LNA, int LNRES, int LNOUT>
__global__ __launch_bounds__(256) void mgemm_k(
    const u16* __restrict__ A, const u16* __restrict__ W,
    const float* __restrict__ bias, const u16* __restrict__ resid,
    void* __restrict__ Cv,
    const float* __restrict__ lnst_in, const float* __restrict__ g_in,
    const float* __restrict__ b_in, float* __restrict__ lnst_out,
    int M, int N, int K, float alpha)
{
    constexpr int MI = BM / 32;   // 16-row fragments per wave
    constexpr int NJ = BN / 32;   // 16-col fragments per wave
    __shared__ u16 As[2][BM][72];
    __shared__ u16 Bs[2][BN][72];
    const int bm = blockIdx.y * BM, bn = blockIdx.x * BN;
    const int tid = threadIdx.x;
    const int wave = tid >> 6, lane = tid & 63;
    const int wr = (wave >> 1) * (BM / 2), wc = (wave & 1) * (BN / 2);
    const int lm = lane & 15, quad = lane >> 4;
    const int sar = (BM == 64) ? (tid >> 2) : (tid >> 3);
    const int sac = (BM == 64) ? ((tid & 3) * 16) : ((tid & 7) * 8);
    const int sbr = (BN == 64) ? (tid >> 2) : (tid >> 3);
    const int sbc = (BN == 64) ? ((tid & 3) * 16) : ((tid & 7) * 8);

    int brow = bn + sbr;
    if (KVMAP) brow = (brow >> 10) * (3 * DM) + DM + (brow & 1023);

    const u16* Arow = A + (size_t)(bm + sar) * K + sac;
    const u16* Wrow = W + (size_t)brow * K + sbc;

    // row stats for LNA (row is K-loop invariant per thread)
    float meanA = 0.f, rstdA = 0.f;
    if (LNA) {
        int rowA = bm + sar;
        float s = lnst_in[rowA * 2], q = lnst_in[rowA * 2 + 1];
        meanA = s * (1.f / DM);
        rstdA = rsqrtf(q * (1.f / DM) - meanA * meanA + 1e-5f);
    }

    us8 a0 = *(const us8*)(Arow);
    us8 a1;
    if (BM == 64) a1 = *(const us8*)(Arow + 8);
    us8 b0 = *(const us8*)(Wrow);
    us8 b1;
    if (BN == 64) b1 = *(const us8*)(Wrow + 8);

    f4 acc[MI][NJ];
#pragma unroll
    for (int i = 0; i < MI; i++)
#pragma unroll
        for (int j = 0; j < NJ; j++) acc[i][j] = (f4)(0.f);

    const int nk = K >> 6;
    if (LNA) {
        *(us8*)&As[0][sar][sac] = lnx8(a0, meanA, rstdA, g_in + sac, b_in + sac);
        if (BM == 64) *(us8*)&As[0][sar][sac + 8] = lnx8(a1, meanA, rstdA, g_in + sac + 8, b_in + sac + 8);
    } else {
        *(us8*)&As[0][sar][sac] = a0;
        if (BM == 64) *(us8*)&As[0][sar][sac + 8] = a1;
    }
    *(us8*)&Bs[0][sbr][sbc] = b0;
    if (BN == 64) *(us8*)&Bs[0][sbr][sbc + 8] = b1;
    __syncthreads();

    for (int t = 0; t < nk; t++) {
        const int cb = t & 1;
        int off = 0;
        if (t + 1 < nk) {
            off = (t + 1) << 6;
            a0 = *(const us8*)(Arow + off);
            if (BM == 64) a1 = *(const us8*)(Arow + off + 8);
            b0 = *(const us8*)(Wrow + off);
            if (BN == 64) b1 = *(const us8*)(Wrow + off + 8);
        }
#pragma unroll
        for (int ks = 0; ks < 2; ks++) {
            s8 af[MI], bfr[NJ];
#pragma unroll
            for (int i = 0; i < MI; i++) af[i] = *(const s8*)&As[cb][wr + i * 16 + lm][ks * 32 + quad * 8];
#pragma unroll
            for (int j = 0; j < NJ; j++) bfr[j] = *(const s8*)&Bs[cb][wc + j * 16 + lm][ks * 32 + quad * 8];
#pragma unroll
            for (int i = 0; i < MI; i++)
#pragma unroll
                for (int j = 0; j < NJ; j++)
                    acc[i][j] = __builtin_amdgcn_mfma_f32_16x16x32_bf16(af[i], bfr[j], acc[i][j], 0, 0, 0);
        }
        if (t + 1 < nk) {
            const int nb = cb ^ 1;
            if (LNA) {
                *(us8*)&As[nb][sar][sac] = lnx8(a0, meanA, rstdA, g_in + off + sac, b_in + off + sac);
                if (BM == 64) *(us8*)&As[nb][sar][sac + 8] = lnx8(a1, meanA, rstdA, g_in + off + sac + 8, b_in + off + sac + 8);
            } else {
                *(us8*)&As[nb][sar][sac] = a0;
                if (BM == 64) *(us8*)&As[nb][sar][sac + 8] = a1;
            }
            *(us8*)&Bs[nb][sbr][sbc] = b0;
            if (BN == 64) *(us8*)&Bs[nb][sbr][sbc + 8] = b1;
            __syncthreads();
        }
    }

    // row stats for LNRES (rows fixed per thread)
    float meanR[MI][4], rstdR[MI][4];
    if (LNRES) {
#pragma unroll
        for (int i = 0; i < MI; i++)
#pragma unroll
            for (int r = 0; r < 4; r++) {
                int m = bm + wr + i * 16 + quad * 4 + r;
                float s = lnst_in[m * 2], q = lnst_in[m * 2 + 1];
                float mn = s * (1.f / DM);
                meanR[i][r] = mn;
                rstdR[i][r] = rsqrtf(q * (1.f / DM) - mn * mn + 1e-5f);
            }
    }
    float so[MI][4], qo[MI][4];
    if (LNOUT) {
#pragma unroll
        for (int i = 0; i < MI; i++)
#pragma unroll
            for (int r = 0; r < 4; r++) { so[i][r] = 0.f; qo[i][r] = 0.f; }
    }

#pragma unroll
    for (int j = 0; j < NJ; j++) {
        int n = bn + wc + j * 16 + lm;
        float bv = bias[n];
        float gR = 0.f, bRv = 0.f;
        if (LNRES) { gR = g_in[n]; bRv = b_in[n]; }
        float dv = 0.f;
        if (PE == 1) dv = expf((float)(n & ~1) * (-9.210340371976184f / (float)DM));
#pragma unroll
        for (int i = 0; i < MI; i++) {
#pragma unroll
            for (int r = 0; r < 4; r++) {
                int m = bm + wr + i * 16 + quad * 4 + r;
                float v = (acc[i][j][r] + bv) * alpha;
                if (PE == 1) {
                    float ang = (float)(m & (SEQ - 1)) * dv;
                    v += (n & 1) ? cosf(ang) : sinf(ang);
                }
                if (PE == 2) { if (n & 1) v += 1.f; }
                if (RELU) v = fmaxf(v, 0.f);
                size_t off = (size_t)m * N + n;
                if (resid) {
                    float rv = b2f(resid[off]);
                    if (LNRES) rv = (rv - meanR[i][r]) * rstdR[i][r] * gR + bRv;
                    v += rv;
                }
                if (OUTF32) ((float*)Cv)[off] = v;
                else        ((u16*)Cv)[off]  = f2b(v);
                if (LNOUT) { so[i][r] += v; qo[i][r] += v * v; }
            }
        }
    }

    if (LNOUT) {
#pragma unroll
        for (int st = 1; st < 16; st <<= 1)
#pragma unroll
            for (int i = 0; i < MI; i++)
#pragma unroll
                for (int r = 0; r < 4; r++) {
                    so[i][r] += __shfl_xor(so[i][r], st);
                    qo[i][r] += __shfl_xor(qo[i][r], st);
                }
        if (lm == 0) {
#pragma unroll
            for (int i = 0; i < MI; i++)
#pragma unroll
                for (int r = 0; r < 4; r++) {
                    int m = bm + wr + i * 16 + quad * 4 + r;
                    atomicAdd(&lnst_out[m * 2],     so[i][r]);
                    atomicAdd(&lnst_out[m * 2 + 1], qo[i][r]);
                }
        }
    }
}

// ============ Fused flash attention (verified R2 structure) ============
template <int CAUSAL>
__global__ __launch_bounds__(256) void flash_k(
    const u16* __restrict__ Q, int qs,
    const u16* __restrict__ Kp, int ks,
    const u16* __restrict__ V, int vs,
    u16* __restrict__ O, int Sq, int Sk)
{
    __shared__ u16 Qs[64][72];
    __shared__ u16 Ks[128][72];
    __shared__ u16 Vs[64][136];
    __shared__ u16 Ps[4][16][136];
    const int bm = blockIdx.x * 64;
    const int bh = blockIdx.y, b = bh >> 3, h = bh & 7;
    const int tid = threadIdx.x;
    const int wave = tid >> 6, lane = tid & 63;
    const int lm = lane & 15, quad = lane >> 4;

    const u16* Qb = Q + (size_t)(b * Sq + bm) * qs + h * HD;
    {
        int r = tid >> 2, c = (tid & 3) * 16;
        *(us8*)&Qs[r][c]     = *(const us8*)(Qb + (size_t)r * qs + c);
        *(us8*)&Qs[r][c + 8] = *(const us8*)(Qb + (size_t)r * qs + c + 8);
    }

    float mrow[4], lrow[4];
    f4 o[4];
#pragma unroll
    for (int r = 0; r < 4; r++) { mrow[r] = -1e30f; lrow[r] = 0.f; }
#pragma unroll
    for (int nt = 0; nt < 4; nt++) o[nt] = (f4)(0.f);

    const u16* Kb = Kp + (size_t)(b * Sk) * ks + h * HD;
    const u16* Vb = V + (size_t)(b * Sk) * vs + h * HD;
    int nkt = Sk >> 7;
    if (CAUSAL) { int lim = (bm + 63) / 128 + 1; if (lim < nkt) nkt = lim; }

    const int vd = tid & 63, vkb = tid >> 6;
    const int kr = tid >> 3, kc8 = (tid & 7) * 8;

    for (int kt = 0; kt < nkt; kt++) {
        const u16* Kt = Kb + ((size_t)kt << 7) * ks;
        const u16* Vt = Vb + ((size_t)kt << 7) * vs;
#pragma unroll
        for (int p = 0; p < 4; p++) {
            int r = p * 32 + kr;
            *(us8*)&Ks[r][kc8] = *(const us8*)(Kt + (size_t)r * ks + kc8);
        }
#pragma unroll
        for (int p = 0; p < 32; p++) {
            int kv = p * 4 + vkb;
            Vs[vd][kv] = Vt[(size_t)kv * vs + vd];
        }
        __syncthreads();

        f4 sa[8];
#pragma unroll
        for (int nt = 0; nt < 8; nt++) sa[nt] = (f4)(0.f);
#pragma unroll
        for (int ks2 = 0; ks2 < 2; ks2++) {
            s8 aq = *(const s8*)&Qs[wave * 16 + lm][ks2 * 32 + quad * 8];
#pragma unroll
            for (int nt = 0; nt < 8; nt++) {
                s8 bk = *(const s8*)&Ks[nt * 16 + lm][ks2 * 32 + quad * 8];
                sa[nt] = __builtin_amdgcn_mfma_f32_16x16x32_bf16(aq, bk, sa[nt], 0, 0, 0);
            }
        }
        float tmx[4] = {-1e30f, -1e30f, -1e30f, -1e30f};
#pragma unroll
        for (int nt = 0; nt < 8; nt++) {
#pragma unroll
            for (int r = 0; r < 4; r++) {
                float v = sa[nt][r] * 0.125f;
                if (CAUSAL) {
                    int col = (kt << 7) + nt * 16 + lm;
                    int row = bm + wave * 16 + quad * 4 + r;
                    if (col > row) v = -1e30f;
                }
                sa[nt][r] = v;
                tmx[r] = fmaxf(tmx[r], v);
            }
        }
#pragma unroll
        for (int st = 1; st < 16; st <<= 1)
#pragma unroll
            for (int r = 0; r < 4; r++) tmx[r] = fmaxf(tmx[r], __shfl_xor(tmx[r], st));
        float al[4];
#pragma unroll
        for (int r = 0; r < 4; r++) {
            float mn = fmaxf(mrow[r], tmx[r]);
            al[r] = __expf(mrow[r] - mn);
            mrow[r] = mn;
        }
        float ts[4] = {0.f, 0.f, 0.f, 0.f};
#pragma unroll
        for (int nt = 0; nt < 8; nt++) {
#pragma unroll
            for (int r = 0; r < 4; r++) {
                float pe = __expf(sa[nt][r] - mrow[r]);
                sa[nt][r] = pe;
                ts[r] += pe;
            }
        }
#pragma unroll
        for (int st = 1; st < 16; st <<= 1)
#pragma unroll
            for (int r = 0; r < 4; r++) ts[r] += __shfl_xor(ts[r], st);
#pragma unroll
        for (int r = 0; r < 4; r++) lrow[r] = lrow[r] * al[r] + ts[r];
#pragma unroll
        for (int nt = 0; nt < 4; nt++)
#pragma unroll
            for (int r = 0; r < 4; r++) o[nt][r] *= al[r];
#pragma unroll
        for (int nt = 0; nt < 8; nt++)
#pragma unroll
            for (int r = 0; r < 4; r++)
                Ps[wave][quad * 4 + r][nt * 16 + lm] = f2b(sa[nt][r]);
#pragma unroll
        for (int kc = 0; kc < 4; kc++) {
            s8 ap = *(const s8*)&Ps[wave][lm][kc * 32 + quad * 8];
#pragma unroll
            for (int nt = 0; nt < 4; nt++) {
                s8 bv = *(const s8*)&Vs[nt * 16 + lm][kc * 32 + quad * 8];
                o[nt] = __builtin_amdgcn_mfma_f32_16x16x32_bf16(ap, bv, o[nt], 0, 0, 0);
            }
        }
        __syncthreads();
    }

    float inv[4];
#pragma unroll
    for (int r = 0; r < 4; r++) inv[r] = 1.f / lrow[r];
#pragma unroll
    for (int nt = 0; nt < 4; nt++) {
#pragma unroll
        for (int r = 0; r < 4; r++) {
            int m = bm + wave * 16 + quad * 4 + r;
            O[(size_t)(b * Sq + m) * DM + h * HD + nt * 16 + lm] = f2b(o[nt][r] * inv[r]);
        }
    }
}

// ---------------- host orchestration ----------------
static inline dim3 mg(int M, int N, int BM, int BN) { return dim3(N / BN, M / BM); }

extern "C" void kernel_launch(void* const* d_in, const int* in_sizes, int n_in,
                              void* d_out, int out_size, void* d_ws, size_t ws_size,
                              hipStream_t stream)
{
    const float* src       = (const float*)d_in[0];
    const float* tgt       = (const float*)d_in[1];
    const float* enc_in_w  = (const float*)d_in[2];
    const float* enc_in_b  = (const float*)d_in[3];
    const float* dec_in_w  = (const float*)d_in[4];
    const float* dec_in_b  = (const float*)d_in[5];
    const float* out_w     = (const float*)d_in[6];
    const float* out_b     = (const float*)d_in[7];
    const float* enc_attn_w = (const float*)d_in[8];
    const float* enc_attn_b = (const float*)d_in[9];
    const float* enc_out_w  = (const float*)d_in[10];
    const float* enc_out_b  = (const float*)d_in[11];
    const float* enc_ff1_w  = (const float*)d_in[12];
    const float* enc_ff1_b  = (const float*)d_in[13];
    const float* enc_ff2_w  = (const float*)d_in[14];
    const float* enc_ff2_b  = (const float*)d_in[15];
    const float* enc_ln1_g  = (const float*)d_in[16];
    const float* enc_ln1_b  = (const float*)d_in[17];
    const float* enc_ln2_g  = (const float*)d_in[18];
    const float* enc_ln2_b  = (const float*)d_in[19];
    const float* dec_sa_w     = (const float*)d_in[20];
    const float* dec_sa_b     = (const float*)d_in[21];
    const float* dec_sa_out_w = (const float*)d_in[22];
    const float* dec_sa_out_b = (const float*)d_in[23];
    const float* dec_ca_w     = (const float*)d_in[24];
    const float* dec_ca_b     = (const float*)d_in[25];
    const float* dec_ca_out_w = (const float*)d_in[26];
    const float* dec_ca_out_b = (const float*)d_in[27];
    const float* dec_ff1_w    = (const float*)d_in[28];
    const float* dec_ff1_b    = (const float*)d_in[29];
    const float* dec_ff2_w    = (const float*)d_in[30];
    const float* dec_ff2_b    = (const float*)d_in[31];
    const float* dec_ln1_g    = (const float*)d_in[32];
    const float* dec_ln1_b    = (const float*)d_in[33];
    const float* dec_ln2_g    = (const float*)d_in[34];
    const float* dec_ln2_b    = (const float*)d_in[35];
    const float* dec_ln3_g    = (const float*)d_in[36];
    const float* dec_ln3_b    = (const float*)d_in[37];

    const int ME = BB * SEQ;  // 2048
    const int MD = BB * TGT;  // 1024
    const int BH = BB * NH;   // 32
    const float SQD = 22.627416997969522f;  // sqrt(512)

    const size_t SZ_ATTN = (size_t)NL * 3 * DM * DM;
    const size_t SZ_OUT  = (size_t)NL * DM * DM;
    const size_t SZ_FF   = (size_t)NL * FFD * DM;

    // ---- workspace layout ----
    float* fp = (float*)d_ws;
    // LN stats: enc 12 sites x 2048 rows x {sum,sumsq}; dec 18 sites x 1024 rows
    const int ENC_ST = 12 * 2048 * 2, DEC_ST = 18 * 1024 * 2;
    float* stats = fp; fp += ENC_ST + DEC_ST;
    float* kvbias = fp; fp += NL * 2 * DM;
    u16* p = (u16*)fp;
    u16* xa   = p; p += (size_t)ME * DM;
    u16* xb   = p; p += (size_t)ME * DM;
    u16* reg1 = p; p += (size_t)ME * FFD;
    u16* tbuf = p; p += (size_t)ME * DM;
    u16* ya   = p; p += (size_t)MD * DM;
    u16* yb   = p; p += (size_t)MD * DM;
    u16* kvall = p; p += (size_t)ME * NL * 2 * DM;
    u16* src_b     = p; p += (size_t)ME * HD;
    u16* tgt_b     = p; p += (size_t)MD * HD;
    u16* enc_in_wb = p; p += (size_t)DM * HD;
    u16* dec_in_wb = p; p += (size_t)DM * HD;
    u16* out_wb    = p; p += (size_t)HD * DM;
    u16* enc_at_wb = p; p += SZ_ATTN;
    u16* enc_ow_wb = p; p += SZ_OUT;
    u16* enc_f1_wb = p; p += SZ_FF;
    u16* enc_f2_wb = p; p += SZ_FF;
    u16* dec_sa_wb = p; p += SZ_ATTN;
    u16* dec_sao_wb = p; p += SZ_OUT;
    u16* dec_ca_wb = p; p += SZ_ATTN;
    u16* dec_cao_wb = p; p += SZ_OUT;
    u16* dec_f1_wb = p; p += SZ_FF;
    u16* dec_f2_wb = p; p += SZ_FF;

    // per-site stats pointers: enc site s of layer i (s=0: post-attn, s=1: post-ff)
    auto eSt = [&](int i, int s) { return stats + (size_t)(i * 2 + s) * 2048 * 2; };
    auto dSt = [&](int i, int s) { return stats + ENC_ST + (size_t)(i * 3 + s) * 1024 * 2; };

    zero_k<<<(ENC_ST + DEC_ST + 255) / 256, 256, 0, stream>>>(stats, ENC_ST + DEC_ST);

    // ===== single batched cast (15 segments; KV weights read via KVMAP) =====
    CastSegs cs;
    int ns = 0;
    auto seg = [&](const float* s, u16* d, size_t n) {
        cs.src[ns] = s; cs.dst[ns] = d;
        cs.cum[ns + 1] = cs.cum[ns] + (int)(n / 4);
        ns++;
    };
    cs.cum[0] = 0;
    seg(src,          src_b,     (size_t)ME * HD);
    seg(tgt,          tgt_b,     (size_t)MD * HD);
    seg(enc_in_w,     enc_in_wb, (size_t)DM * HD);
    seg(dec_in_w,     dec_in_wb, (size_t)DM * HD);
    seg(out_w,        out_wb,    (size_t)HD * DM);
    seg(enc_attn_w,   enc_at_wb, SZ_ATTN);
    seg(enc_out_w,    enc_ow_wb, SZ_OUT);
    seg(enc_ff1_w,    enc_f1_wb, SZ_FF);
    seg(enc_ff2_w,    enc_f2_wb, SZ_FF);
    seg(dec_sa_w,     dec_sa_wb, SZ_ATTN);
    seg(dec_sa_out_w, dec_sao_wb, SZ_OUT);
    seg(dec_ca_w,     dec_ca_wb, SZ_ATTN);
    seg(dec_ca_out_w, dec_cao_wb, SZ_OUT);
    seg(dec_ff1_w,    dec_f1_wb, SZ_FF);
    seg(dec_ff2_w,    dec_f2_wb, SZ_FF);
    cs.nseg = ns;
    castseg_k<<<cs.cum[ns] >> 11, 256, 0, stream>>>(cs);
    kvbias_k<<<(NL * 2 * DM + 255) / 256, 256, 0, stream>>>(dec_ca_b, kvbias);

    // ===== encoder =====
    mgemm_k<0, 0, 64, 32, 1, 0, 0, 0, 0><<<mg(ME, DM, 64, 32), 256, 0, stream>>>(
        src_b, enc_in_wb, enc_in_b, nullptr, xa, nullptr, nullptr, nullptr, nullptr, ME, DM, HD, SQD);

    u16* cur = xa; u16* alt = xb;
    for (int i = 0; i < NL; i++) {
        const u16* W = enc_at_wb + (size_t)i * 3 * DM * DM;
        const float* Bw = enc_attn_b + (size_t)i * 3 * DM;
        const float* pSt = (i > 0) ? eSt(i - 1, 1) : nullptr;          // prev ln2 stats
        const float* pG  = enc_ln2_g + (size_t)(i - 1) * DM;
        const float* pB  = enc_ln2_b + (size_t)(i - 1) * DM;
        // QKV (A = prev-layer pre-LN tensor, or raw in-proj for i==0)
        if (i == 0)
            mgemm_k<0, 0, 64, 64, 0, 0, 0, 0, 0><<<mg(ME, 3 * DM, 64, 64), 256, 0, stream>>>(
                cur, W, Bw, nullptr, reg1, nullptr, nullptr, nullptr, nullptr, ME, 3 * DM, DM, 1.f);
        else
            mgemm_k<0, 0, 64, 64, 0, 0, 1, 0, 0><<<mg(ME, 3 * DM, 64, 64), 256, 0, stream>>>(
                cur, W, Bw, nullptr, reg1, pSt, pG, pB, nullptr, ME, 3 * DM, DM, 1.f);
        flash_k<0><<<dim3(SEQ / 64, BH), 256, 0, stream>>>(reg1, 3 * DM, reg1 + DM, 3 * DM, reg1 + 2 * DM, 3 * DM, tbuf, SEQ, SEQ);
        // attn-out + resid(prev, LN'd on read) -> raw y1, stats E1[i]
        if (i == 0)
            mgemm_k<0, 0, 32, 32, 0, 0, 0, 0, 1><<<mg(ME, DM, 32, 32), 256, 0, stream>>>(
                tbuf, enc_ow_wb + (size_t)i * DM * DM, enc_out_b + (size_t)i * DM, cur, alt,
                nullptr, nullptr, nullptr, eSt(i, 0), ME, DM, DM, 1.f);
        else
            mgemm_k<0, 0, 32, 32, 0, 0, 0, 1, 1><<<mg(ME, DM, 32, 32), 256, 0, stream>>>(
                tbuf, enc_ow_wb + (size_t)i * DM * DM, enc_out_b + (size_t)i * DM, cur, alt,
                pSt, pG, pB, eSt(i, 0), ME, DM, DM, 1.f);
        { u16* t = cur; cur = alt; alt = t; }
        // ff1 (A = y1 with ln1 on read)
        mgemm_k<1, 0, 64, 64, 0, 0, 1, 0, 0><<<mg(ME, FFD, 64, 64), 256, 0, stream>>>(
            cur, enc_f1_wb + (size_t)i * FFD * DM, enc_ff1_b + (size_t)i * FFD, nullptr, reg1,
            eSt(i, 0), enc_ln1_g + (size_t)i * DM, enc_ln1_b + (size_t)i * DM, nullptr, ME, FFD, DM, 1.f);
        // ff2 + resid(y1 w/ ln1) -> raw y2, stats E2[i]
        mgemm_k<0, 0, 32, 32, 0, 0, 0, 1, 1><<<mg(ME, DM, 32, 32), 256, 0, stream>>>(
            reg1, enc_f2_wb + (size_t)i * DM * FFD, enc_ff2_b + (size_t)i * DM, cur, alt,
            eSt(i, 0), enc_ln1_g + (size_t)i * DM, enc_ln1_b + (size_t)i * DM, eSt(i, 1), ME, DM, FFD, 1.f);
        { u16* t = cur; cur = alt; alt = t; }
    }
    u16* mem = cur;  // raw y2[5]; LN ctx = (E2[5], enc_ln2[5])

    // ===== all 6 layers' cross-attn K/V projections in one GEMM (KVMAP, LN on A) =====
    mgemm_k<0, 0, 64, 64, 0, 1, 1, 0, 0><<<mg(ME, NL * 2 * DM, 64, 64), 256, 0, stream>>>(
        mem, dec_ca_wb, kvbias, nullptr, kvall,
        eSt(5, 1), enc_ln2_g + (size_t)5 * DM, enc_ln2_b + (size_t)5 * DM, nullptr, ME, NL * 2 * DM, DM, 1.f);

    // ===== decoder =====
    mgemm_k<0, 0, 32, 32, 2, 0, 0, 0, 0><<<mg(MD, DM, 32, 32), 256, 0, stream>>>(
        tgt_b, dec_in_wb, dec_in_b, nullptr, ya, nullptr, nullptr, nullptr, nullptr, MD, DM, HD, SQD);

    u16* dc = ya; u16* da = yb;
    for (int i = 0; i < NL; i++) {
        const u16* W = dec_sa_wb + (size_t)i * 3 * DM * DM;
        const float* Bw = dec_sa_b + (size_t)i * 3 * DM;
        const float* pSt = (i > 0) ? dSt(i - 1, 2) : nullptr;          // prev ln3 stats
        const float* pG  = dec_ln3_g + (size_t)(i - 1) * DM;
        const float* pB  = dec_ln3_b + (size_t)(i - 1) * DM;
        // --- self-attention QKV ---
        if (i == 0)
            mgemm_k<0, 0, 64, 32, 0, 0, 0, 0, 0><<<mg(MD, 3 * DM, 64, 32), 256, 0, stream>>>(
                dc, W, Bw, nullptr, reg1, nullptr, nullptr, nullptr, nullptr, MD, 3 * DM, DM, 1.f);
        else
            mgemm_k<0, 0, 64, 32, 0, 0, 1, 0, 0><<<mg(MD, 3 * DM, 64, 32), 256, 0, stream>>>(
                dc, W, Bw, nullptr, reg1, pSt, pG, pB, nullptr, MD, 3 * DM, DM, 1.f);
        flash_k<1><<<dim3(TGT / 64, BH), 256, 0, stream>>>(reg1, 3 * DM, reg1 + DM, 3 * DM, reg1 + 2 * DM, 3 * DM, tbuf, TGT, TGT);
        if (i == 0)
            mgemm_k<0, 0, 32, 32, 0, 0, 0, 0, 1><<<mg(MD, DM, 32, 32), 256, 0, stream>>>(
                tbuf, dec_sao_wb + (size_t)i * DM * DM, dec_sa_out_b + (size_t)i * DM, dc, da,
                nullptr, nullptr, nullptr, dSt(i, 0), MD, DM, DM, 1.f);
        else
            mgemm_k<0, 0, 32, 32, 0, 0, 0, 1, 1><<<mg(MD, DM, 32, 32), 256, 0, stream>>>(
                tbuf, dec_sao_wb + (size_t)i * DM * DM, dec_sa_out_b + (size_t)i * DM, dc, da,
                pSt, pG, pB, dSt(i, 0), MD, DM, DM, 1.f);
        { u16* t = dc; dc = da; da = t; }

        // --- cross-attention: Q proj (A = D1 w/ ln1), K/V precomputed ---
        u16* qbuf = reg1;
        mgemm_k<0, 0, 32, 32, 0, 0, 1, 0, 0><<<mg(MD, DM, 32, 32), 256, 0, stream>>>(
            dc, dec_ca_wb + (size_t)i * 3 * DM * DM, dec_ca_b + (size_t)i * 3 * DM, nullptr, qbuf,
            dSt(i, 0), dec_ln1_g + (size_t)i * DM, dec_ln1_b + (size_t)i * DM, nullptr, MD, DM, DM, 1.f);
        const u16* kvl = kvall + (size_t)i * 2 * DM;
        flash_k<0><<<dim3(TGT / 64, BH), 256, 0, stream>>>(qbuf, DM, kvl, NL * 2 * DM, kvl + DM, NL * 2 * DM, tbuf, TGT, SEQ);
        mgemm_k<0, 0, 32, 32, 0, 0, 0, 1, 1><<<mg(MD, DM, 32, 32), 256, 0, stream>>>(
            tbuf, dec_cao_wb + (size_t)i * DM * DM, dec_ca_out_b + (size_t)i * DM, dc, da,
            dSt(i, 0), dec_ln1_g + (size_t)i * DM, dec_ln1_b + (size_t)i * DM, dSt(i, 1), MD, DM, DM, 1.f);
        { u16* t = dc; dc = da; da = t; }

        // --- feed-forward ---
        mgemm_k<1, 0, 64, 32, 0, 0, 1, 0, 0><<<mg(MD, FFD, 64, 32), 256, 0, stream>>>(
            dc, dec_f1_wb + (size_t)i * FFD * DM, dec_ff1_b + (size_t)i * FFD, nullptr, reg1,
            dSt(i, 1), dec_ln2_g + (size_t)i * DM, dec_ln2_b + (size_t)i * DM, nullptr, MD, FFD, DM, 1.f);
        mgemm_k<0, 0, 32, 32, 0, 0, 0, 1, 1><<<mg(MD, DM, 32, 32), 256, 0, stream>>>(
            reg1, dec_f2_wb + (size_t)i * DM * FFD, dec_ff2_b + (size_t)i * DM, dc, da,
            dSt(i, 1), dec_ln2_g + (size_t)i * DM, dec_ln2_b + (size_t)i * DM, dSt(i, 2), MD, DM, FFD, 1.f);
        { u16* t = dc; dc = da; da = t; }
    }

    // ===== final projection (A = D3[5] w/ ln3; N=64, fp32 into d_out) =====
    mgemm_k<0, 1, 32, 32, 0, 0, 1, 0, 0><<<mg(MD, HD, 32, 32), 256, 0, stream>>>(
        dc, out_wb, out_b, nullptr, (float*)d_out,
        dSt(5, 2), dec_ln3_g + (size_t)5 * DM, dec_ln3_b + (size_t)5 * DM, nullptr, MD, HD, DM, 1.f);
}

// Round 9
// 1220.182 us; speedup vs baseline: 1.3686x; 1.3686x over previous
//
#include <hip/hip_runtime.h>
#include <hip/hip_bf16.h>
#include <math.h>

#define BB 4
#define SEQ 512
#define TGT 256
#define DM 512
#define FFD 2048
#define NH 8
#define HD 64
#define NL 6

typedef unsigned short u16;
typedef __attribute__((ext_vector_type(4))) float f4;
typedef __attribute__((ext_vector_type(4))) unsigned short us4;
typedef __attribute__((ext_vector_type(8))) unsigned short us8;
typedef __attribute__((ext_vector_type(8))) short s8;

__device__ inline u16 f2b(float f) {
    __hip_bfloat16 h = __float2bfloat16(f);
    return *reinterpret_cast<u16*>(&h);
}
__device__ inline float b2f(u16 u) {
    unsigned int x = ((unsigned int)u) << 16;
    float f;
    __builtin_memcpy(&f, &x, 4);
    return f;
}
__device__ inline us4 cvt4(f4 v) {
    us4 u;
    u.x = f2b(v.x); u.y = f2b(v.y); u.z = f2b(v.z); u.w = f2b(v.w);
    return u;
}

// ---------------- batched fp32 -> bf16 cast ----------------
// Pinned at ~75us / 2.4 TB/s across three access-pattern variants. Leave it.
// R8 lesson: do NOT fuse the cast/LN into consumers -- consumer GEMMs re-read
// per K-step, multiplying the elementwise work by the reuse factor.
struct CastSegs {
    const float* src[24];
    u16* dst[24];
    int cum[25];   // cumulative n4 (f4 groups)
    int nseg;
};

__global__ __launch_bounds__(256) void castseg_k(CastSegs cs)
{
    const int g0 = blockIdx.x << 11;           // first f4-group of this block
    int s = 0;
    while (g0 >= cs.cum[s + 1]) s++;           // block-uniform search
    const f4* __restrict__ sp = (const f4*)cs.src[s];
    us4* __restrict__ dp = (us4*)cs.dst[s];
    const int base = g0 - cs.cum[s] + (int)threadIdx.x;

    f4 v[8];
#pragma unroll
    for (int k = 0; k < 8; k++) v[k] = sp[base + (k << 8)];
#pragma unroll
    for (int k = 0; k < 8; k++) dp[base + (k << 8)] = cvt4(v[k]);
}

// ---------------- stack decoder cross-attn KV biases: [6][1024] fp32 ----------------
__global__ void kvbias_k(const float* __restrict__ dec_ca_b, float* __restrict__ out)
{
    int idx = blockIdx.x * blockDim.x + threadIdx.x;
    if (idx >= NL * 2 * DM) return;
    int layer = idx >> 10, j = idx & 1023;
    out[idx] = dec_ca_b[layer * 3 * DM + DM + j];
}

// ============ MFMA GEMM, bf16, BMxBN tile, BK=64, double-buffered LDS ============
// PE: 0 none, 1 encoder sinusoidal pe, 2 decoder pe row 0
// KVMAP: remap B row n -> layer*3*DM + DM + (n&1023) (kvall GEMM).
// BN templated (R7 win): these GEMMs are latency-bound (R5: MfmaUtil 7.6% @
// occ 19%); blocks/CU + grid coverage is the operative lever (R6 +13us,
// R7 +38us). BN=32 doubles coverage for the N=512 GEMMs.
template <int RELU, int OUTF32, int BM, int BN, int PE, int KVMAP>
__global__ __launch_bounds__(256) void mgemm_k(
    const u16* __restrict__ A, const u16* __restrict__ W,
    const float* __restrict__ bias, const u16* __restrict__ resid,
    void* __restrict__ Cv, int M, int N, int K, float alpha)
{
    constexpr int MI = BM / 32;   // 16-row fragments per wave
    constexpr int NJ = BN / 32;   // 16-col fragments per wave
    __shared__ u16 As[2][BM][72];
    __shared__ u16 Bs[2][BN][72];
    const int bm = blockIdx.y * BM, bn = blockIdx.x * BN;
    const int tid = threadIdx.x;
    const int wave = tid >> 6, lane = tid & 63;
    const int wr = (wave >> 1) * (BM / 2), wc = (wave & 1) * (BN / 2);
    const int lm = lane & 15, quad = lane >> 4;
    const int sar = (BM == 64) ? (tid >> 2) : (tid >> 3);
    const int sac = (BM == 64) ? ((tid & 3) * 16) : ((tid & 7) * 8);
    const int sbr = (BN == 64) ? (tid >> 2) : (tid >> 3);
    const int sbc = (BN == 64) ? ((tid & 3) * 16) : ((tid & 7) * 8);

    int brow = bn + sbr;
    if (KVMAP) brow = (brow >> 10) * (3 * DM) + DM + (brow & 1023);

    const u16* Arow = A + (size_t)(bm + sar) * K + sac;
    const u16* Wrow = W + (size_t)brow * K + sbc;

    us8 a0 = *(const us8*)(Arow);
    us8 a1;
    if (BM == 64) a1 = *(const us8*)(Arow + 8);
    us8 b0 = *(const us8*)(Wrow);
    us8 b1;
    if (BN == 64) b1 = *(const us8*)(Wrow + 8);

    f4 acc[MI][NJ];
#pragma unroll
    for (int i = 0; i < MI; i++)
#pragma unroll
        for (int j = 0; j < NJ; j++) acc[i][j] = (f4)(0.f);

    const int nk = K >> 6;
    *(us8*)&As[0][sar][sac] = a0;
    if (BM == 64) *(us8*)&As[0][sar][sac + 8] = a1;
    *(us8*)&Bs[0][sbr][sbc] = b0;
    if (BN == 64) *(us8*)&Bs[0][sbr][sbc + 8] = b1;
    __syncthreads();

    for (int t = 0; t < nk; t++) {
        const int cb = t & 1;
        if (t + 1 < nk) {
            int off = (t + 1) << 6;
            a0 = *(const us8*)(Arow + off);
            if (BM == 64) a1 = *(const us8*)(Arow + off + 8);
            b0 = *(const us8*)(Wrow + off);
            if (BN == 64) b1 = *(const us8*)(Wrow + off + 8);
        }
#pragma unroll
        for (int ks = 0; ks < 2; ks++) {
            s8 af[MI], bfr[NJ];
#pragma unroll
            for (int i = 0; i < MI; i++) af[i] = *(const s8*)&As[cb][wr + i * 16 + lm][ks * 32 + quad * 8];
#pragma unroll
            for (int j = 0; j < NJ; j++) bfr[j] = *(const s8*)&Bs[cb][wc + j * 16 + lm][ks * 32 + quad * 8];
#pragma unroll
            for (int i = 0; i < MI; i++)
#pragma unroll
                for (int j = 0; j < NJ; j++)
                    acc[i][j] = __builtin_amdgcn_mfma_f32_16x16x32_bf16(af[i], bfr[j], acc[i][j], 0, 0, 0);
        }
        if (t + 1 < nk) {
            const int nb = cb ^ 1;
            *(us8*)&As[nb][sar][sac] = a0;
            if (BM == 64) *(us8*)&As[nb][sar][sac + 8] = a1;
            *(us8*)&Bs[nb][sbr][sbc] = b0;
            if (BN == 64) *(us8*)&Bs[nb][sbr][sbc + 8] = b1;
            __syncthreads();
        }
    }

#pragma unroll
    for (int j = 0; j < NJ; j++) {
        int n = bn + wc + j * 16 + lm;
        float bv = bias[n];
        float dv = 0.f;
        if (PE == 1) dv = expf((float)(n & ~1) * (-9.210340371976184f / (float)DM));
#pragma unroll
        for (int i = 0; i < MI; i++) {
#pragma unroll
            for (int r = 0; r < 4; r++) {
                int m = bm + wr + i * 16 + quad * 4 + r;
                float v = (acc[i][j][r] + bv) * alpha;
                if (PE == 1) {
                    float ang = (float)(m & (SEQ - 1)) * dv;
                    v += (n & 1) ? cosf(ang) : sinf(ang);
                }
                if (PE == 2) { if (n & 1) v += 1.f; }
                if (RELU) v = fmaxf(v, 0.f);
                size_t off = (size_t)m * N + n;
                if (resid) v += b2f(resid[off]);
                if (OUTF32) ((float*)Cv)[off] = v;
                else        ((u16*)Cv)[off]  = f2b(v);
            }
        }
    }
}

// ============ Fused flash attention ============
// QBLK templated (R9): decoder sites (Sq=256) launched only 128 blocks on
// 256 CUs (half chip idle). QBLK=32 / 128-thread blocks doubles the grid to
// 256 at the same total wave count; LDS 62.5KB -> 49KB. Encoder keeps
// QBLK=64 (already 256 blocks; shrinking would double its staging work).
template <int CAUSAL, int QBLK>
__global__ __launch_bounds__(QBLK * 4) void flash_k(
    const u16* __restrict__ Q, int qs,
    const u16* __restrict__ Kp, int ks,
    const u16* __restrict__ V, int vs,
    u16* __restrict__ O, int Sq, int Sk)
{
    constexpr int NW = QBLK / 16;          // waves per block
    __shared__ u16 Qs[QBLK][72];
    __shared__ u16 Ks[128][72];
    __shared__ u16 Vs[64][136];
    __shared__ u16 Ps[NW][16][136];
    const int bm = blockIdx.x * QBLK;
    const int bh = blockIdx.y, b = bh >> 3, h = bh & 7;
    const int tid = threadIdx.x;
    const int wave = tid >> 6, lane = tid & 63;
    const int lm = lane & 15, quad = lane >> 4;

    const u16* Qb = Q + (size_t)(b * Sq + bm) * qs + h * HD;
    {
        int r = tid >> 2, c = (tid & 3) * 16;
        *(us8*)&Qs[r][c]     = *(const us8*)(Qb + (size_t)r * qs + c);
        *(us8*)&Qs[r][c + 8] = *(const us8*)(Qb + (size_t)r * qs + c + 8);
    }

    float mrow[4], lrow[4];
    f4 o[4];
#pragma unroll
    for (int r = 0; r < 4; r++) { mrow[r] = -1e30f; lrow[r] = 0.f; }
#pragma unroll
    for (int nt = 0; nt < 4; nt++) o[nt] = (f4)(0.f);

    const u16* Kb = Kp + (size_t)(b * Sk) * ks + h * HD;
    const u16* Vb = V + (size_t)(b * Sk) * vs + h * HD;
    int nkt = Sk >> 7;
    if (CAUSAL) { int lim = (bm + QBLK - 1) / 128 + 1; if (lim < nkt) nkt = lim; }

    constexpr int KRP = QBLK * 4 / 8;      // K rows staged per pass (threads/8)
    const int kr = tid >> 3, kc8 = (tid & 7) * 8;
    const int vd = tid & 63, vkb = tid >> 6;   // 0..NW-1

    for (int kt = 0; kt < nkt; kt++) {
        const u16* Kt = Kb + ((size_t)kt << 7) * ks;
        const u16* Vt = Vb + ((size_t)kt << 7) * vs;
#pragma unroll
        for (int p = 0; p < 128 / KRP; p++) {
            int r = p * KRP + kr;
            *(us8*)&Ks[r][kc8] = *(const us8*)(Kt + (size_t)r * ks + kc8);
        }
#pragma unroll
        for (int p = 0; p < 128 / NW; p++) {
            int kv = p * NW + vkb;
            Vs[vd][kv] = Vt[(size_t)kv * vs + vd];
        }
        __syncthreads();

        f4 sa[8];
#pragma unroll
        for (int nt = 0; nt < 8; nt++) sa[nt] = (f4)(0.f);
#pragma unroll
        for (int ks2 = 0; ks2 < 2; ks2++) {
            s8 aq = *(const s8*)&Qs[wave * 16 + lm][ks2 * 32 + quad * 8];
#pragma unroll
            for (int nt = 0; nt < 8; nt++) {
                s8 bk = *(const s8*)&Ks[nt * 16 + lm][ks2 * 32 + quad * 8];
                sa[nt] = __builtin_amdgcn_mfma_f32_16x16x32_bf16(aq, bk, sa[nt], 0, 0, 0);
            }
        }
        float tmx[4] = {-1e30f, -1e30f, -1e30f, -1e30f};
#pragma unroll
        for (int nt = 0; nt < 8; nt++) {
#pragma unroll
            for (int r = 0; r < 4; r++) {
                float v = sa[nt][r] * 0.125f;
                if (CAUSAL) {
                    int col = (kt << 7) + nt * 16 + lm;
                    int row = bm + wave * 16 + quad * 4 + r;
                    if (col > row) v = -1e30f;
                }
                sa[nt][r] = v;
                tmx[r] = fmaxf(tmx[r], v);
            }
        }
#pragma unroll
        for (int st = 1; st < 16; st <<= 1)
#pragma unroll
            for (int r = 0; r < 4; r++) tmx[r] = fmaxf(tmx[r], __shfl_xor(tmx[r], st));
        float al[4];
#pragma unroll
        for (int r = 0; r < 4; r++) {
            float mn = fmaxf(mrow[r], tmx[r]);
            al[r] = __expf(mrow[r] - mn);
            mrow[r] = mn;
        }
        float ts[4] = {0.f, 0.f, 0.f, 0.f};
#pragma unroll
        for (int nt = 0; nt < 8; nt++) {
#pragma unroll
            for (int r = 0; r < 4; r++) {
                float pe = __expf(sa[nt][r] - mrow[r]);
                sa[nt][r] = pe;
                ts[r] += pe;
            }
        }
#pragma unroll
        for (int st = 1; st < 16; st <<= 1)
#pragma unroll
            for (int r = 0; r < 4; r++) ts[r] += __shfl_xor(ts[r], st);
#pragma unroll
        for (int r = 0; r < 4; r++) lrow[r] = lrow[r] * al[r] + ts[r];
#pragma unroll
        for (int nt = 0; nt < 4; nt++)
#pragma unroll
            for (int r = 0; r < 4; r++) o[nt][r] *= al[r];
#pragma unroll
        for (int nt = 0; nt < 8; nt++)
#pragma unroll
            for (int r = 0; r < 4; r++)
                Ps[wave][quad * 4 + r][nt * 16 + lm] = f2b(sa[nt][r]);
#pragma unroll
        for (int kc = 0; kc < 4; kc++) {
            s8 ap = *(const s8*)&Ps[wave][lm][kc * 32 + quad * 8];
#pragma unroll
            for (int nt = 0; nt < 4; nt++) {
                s8 bv = *(const s8*)&Vs[nt * 16 + lm][kc * 32 + quad * 8];
                o[nt] = __builtin_amdgcn_mfma_f32_16x16x32_bf16(ap, bv, o[nt], 0, 0, 0);
            }
        }
        __syncthreads();
    }

    float inv[4];
#pragma unroll
    for (int r = 0; r < 4; r++) inv[r] = 1.f / lrow[r];
#pragma unroll
    for (int nt = 0; nt < 4; nt++) {
#pragma unroll
        for (int r = 0; r < 4; r++) {
            int m = bm + wave * 16 + quad * 4 + r;
            O[(size_t)(b * Sq + m) * DM + h * HD + nt * 16 + lm] = f2b(o[nt][r] * inv[r]);
        }
    }
}

// ---------------- layernorm: 1 wave per row of 512, no barriers ----------------
__global__ __launch_bounds__(256) void ln_k(u16* __restrict__ x,
                                            const float* __restrict__ g,
                                            const float* __restrict__ b)
{
    const int wave = threadIdx.x >> 6, lane = threadIdx.x & 63;
    const int row = blockIdx.x * 4 + wave;
    u16* xr = x + (size_t)row * DM + lane * 8;
    us8 v8 = *(const us8*)xr;
    float v[8];
    float s = 0.f;
#pragma unroll
    for (int e = 0; e < 8; e++) { v[e] = b2f(v8[e]); s += v[e]; }
#pragma unroll
    for (int st = 1; st < 64; st <<= 1) s += __shfl_xor(s, st);
    float mean = s * (1.f / DM);
    float q = 0.f;
#pragma unroll
    for (int e = 0; e < 8; e++) { float d = v[e] - mean; q += d * d; }
#pragma unroll
    for (int st = 1; st < 64; st <<= 1) q += __shfl_xor(q, st);
    float rstd = rsqrtf(q * (1.f / DM) + 1e-5f);
    f4 g0 = *(const f4*)(g + lane * 8), g1 = *(const f4*)(g + lane * 8 + 4);
    f4 b0 = *(const f4*)(b + lane * 8), b1 = *(const f4*)(b + lane * 8 + 4);
    us8 o;
#pragma unroll
    for (int e = 0; e < 4; e++) {
        o[e]     = f2b((v[e]     - mean) * rstd * g0[e] + b0[e]);
        o[e + 4] = f2b((v[e + 4] - mean) * rstd * g1[e] + b1[e]);
    }
    *(us8*)xr = o;
}

// ---------------- host orchestration ----------------
static inline dim3 mg(int M, int N, int BM, int BN) { return dim3(N / BN, M / BM); }

extern "C" void kernel_launch(void* const* d_in, const int* in_sizes, int n_in,
                              void* d_out, int out_size, void* d_ws, size_t ws_size,
                              hipStream_t stream)
{
    const float* src       = (const float*)d_in[0];
    const float* tgt       = (const float*)d_in[1];
    const float* enc_in_w  = (const float*)d_in[2];
    const float* enc_in_b  = (const float*)d_in[3];
    const float* dec_in_w  = (const float*)d_in[4];
    const float* dec_in_b  = (const float*)d_in[5];
    const float* out_w     = (const float*)d_in[6];
    const float* out_b     = (const float*)d_in[7];
    const float* enc_attn_w = (const float*)d_in[8];
    const float* enc_attn_b = (const float*)d_in[9];
    const float* enc_out_w  = (const float*)d_in[10];
    const float* enc_out_b  = (const float*)d_in[11];
    const float* enc_ff1_w  = (const float*)d_in[12];
    const float* enc_ff1_b  = (const float*)d_in[13];
    const float* enc_ff2_w  = (const float*)d_in[14];
    const float* enc_ff2_b  = (const float*)d_in[15];
    const float* enc_ln1_g  = (const float*)d_in[16];
    const float* enc_ln1_b  = (const float*)d_in[17];
    const float* enc_ln2_g  = (const float*)d_in[18];
    const float* enc_ln2_b  = (const float*)d_in[19];
    const float* dec_sa_w     = (const float*)d_in[20];
    const float* dec_sa_b     = (const float*)d_in[21];
    const float* dec_sa_out_w = (const float*)d_in[22];
    const float* dec_sa_out_b = (const float*)d_in[23];
    const float* dec_ca_w     = (const float*)d_in[24];
    const float* dec_ca_b     = (const float*)d_in[25];
    const float* dec_ca_out_w = (const float*)d_in[26];
    const float* dec_ca_out_b = (const float*)d_in[27];
    const float* dec_ff1_w    = (const float*)d_in[28];
    const float* dec_ff1_b    = (const float*)d_in[29];
    const float* dec_ff2_w    = (const float*)d_in[30];
    const float* dec_ff2_b    = (const float*)d_in[31];
    const float* dec_ln1_g    = (const float*)d_in[32];
    const float* dec_ln1_b    = (const float*)d_in[33];
    const float* dec_ln2_g    = (const float*)d_in[34];
    const float* dec_ln2_b    = (const float*)d_in[35];
    const float* dec_ln3_g    = (const float*)d_in[36];
    const float* dec_ln3_b    = (const float*)d_in[37];

    const int ME = BB * SEQ;  // 2048
    const int MD = BB * TGT;  // 1024
    const int BH = BB * NH;   // 32
    const float SQD = 22.627416997969522f;  // sqrt(512)

    const size_t SZ_ATTN = (size_t)NL * 3 * DM * DM;
    const size_t SZ_OUT  = (size_t)NL * DM * DM;
    const size_t SZ_FF   = (size_t)NL * FFD * DM;

    // ---- workspace layout ----
    float* fp = (float*)d_ws;
    float* kvbias = fp; fp += NL * 2 * DM;
    u16* p = (u16*)fp;
    u16* xa   = p; p += (size_t)ME * DM;
    u16* xb   = p; p += (size_t)ME * DM;
    u16* reg1 = p; p += (size_t)ME * FFD;
    u16* tbuf = p; p += (size_t)ME * DM;
    u16* ya   = p; p += (size_t)MD * DM;
    u16* yb   = p; p += (size_t)MD * DM;
    u16* kvall = p; p += (size_t)ME * NL * 2 * DM;
    u16* src_b     = p; p += (size_t)ME * HD;
    u16* tgt_b     = p; p += (size_t)MD * HD;
    u16* enc_in_wb = p; p += (size_t)DM * HD;
    u16* dec_in_wb = p; p += (size_t)DM * HD;
    u16* out_wb    = p; p += (size_t)HD * DM;
    u16* enc_at_wb = p; p += SZ_ATTN;
    u16* enc_ow_wb = p; p += SZ_OUT;
    u16* enc_f1_wb = p; p += SZ_FF;
    u16* enc_f2_wb = p; p += SZ_FF;
    u16* dec_sa_wb = p; p += SZ_ATTN;
    u16* dec_sao_wb = p; p += SZ_OUT;
    u16* dec_ca_wb = p; p += SZ_ATTN;
    u16* dec_cao_wb = p; p += SZ_OUT;
    u16* dec_f1_wb = p; p += SZ_FF;
    u16* dec_f2_wb = p; p += SZ_FF;

    // ===== single batched cast (15 segments; KV weights read via KVMAP) =====
    CastSegs cs;
    int ns = 0;
    auto seg = [&](const float* s, u16* d, size_t n) {
        cs.src[ns] = s; cs.dst[ns] = d;
        cs.cum[ns + 1] = cs.cum[ns] + (int)(n / 4);
        ns++;
    };
    cs.cum[0] = 0;
    seg(src,          src_b,     (size_t)ME * HD);
    seg(tgt,          tgt_b,     (size_t)MD * HD);
    seg(enc_in_w,     enc_in_wb, (size_t)DM * HD);
    seg(dec_in_w,     dec_in_wb, (size_t)DM * HD);
    seg(out_w,        out_wb,    (size_t)HD * DM);
    seg(enc_attn_w,   enc_at_wb, SZ_ATTN);
    seg(enc_out_w,    enc_ow_wb, SZ_OUT);
    seg(enc_ff1_w,    enc_f1_wb, SZ_FF);
    seg(enc_ff2_w,    enc_f2_wb, SZ_FF);
    seg(dec_sa_w,     dec_sa_wb, SZ_ATTN);
    seg(dec_sa_out_w, dec_sao_wb, SZ_OUT);
    seg(dec_ca_w,     dec_ca_wb, SZ_ATTN);
    seg(dec_ca_out_w, dec_cao_wb, SZ_OUT);
    seg(dec_ff1_w,    dec_f1_wb, SZ_FF);
    seg(dec_ff2_w,    dec_f2_wb, SZ_FF);
    cs.nseg = ns;
    castseg_k<<<cs.cum[ns] >> 11, 256, 0, stream>>>(cs);
    kvbias_k<<<(NL * 2 * DM + 255) / 256, 256, 0, stream>>>(dec_ca_b, kvbias);

    // ===== encoder =====
    mgemm_k<0, 0, 64, 32, 1, 0><<<mg(ME, DM, 64, 32), 256, 0, stream>>>(src_b, enc_in_wb, enc_in_b, nullptr, xa, ME, DM, HD, SQD);

    u16* cur = xa; u16* alt = xb;
    for (int i = 0; i < NL; i++) {
        const u16* W = enc_at_wb + (size_t)i * 3 * DM * DM;
        const float* Bw = enc_attn_b + (size_t)i * 3 * DM;
        mgemm_k<0, 0, 64, 64, 0, 0><<<mg(ME, 3 * DM, 64, 64), 256, 0, stream>>>(cur, W, Bw, nullptr, reg1, ME, 3 * DM, DM, 1.f);
        flash_k<0, 64><<<dim3(SEQ / 64, BH), 256, 0, stream>>>(reg1, 3 * DM, reg1 + DM, 3 * DM, reg1 + 2 * DM, 3 * DM, tbuf, SEQ, SEQ);
        mgemm_k<0, 0, 32, 32, 0, 0><<<mg(ME, DM, 32, 32), 256, 0, stream>>>(tbuf, enc_ow_wb + (size_t)i * DM * DM, enc_out_b + (size_t)i * DM, cur, alt, ME, DM, DM, 1.f);
        ln_k<<<ME / 4, 256, 0, stream>>>(alt, enc_ln1_g + (size_t)i * DM, enc_ln1_b + (size_t)i * DM);
        { u16* t = cur; cur = alt; alt = t; }
        mgemm_k<1, 0, 64, 64, 0, 0><<<mg(ME, FFD, 64, 64), 256, 0, stream>>>(cur, enc_f1_wb + (size_t)i * FFD * DM, enc_ff1_b + (size_t)i * FFD, nullptr, reg1, ME, FFD, DM, 1.f);
        mgemm_k<0, 0, 32, 32, 0, 0><<<mg(ME, DM, 32, 32), 256, 0, stream>>>(reg1, enc_f2_wb + (size_t)i * DM * FFD, enc_ff2_b + (size_t)i * DM, cur, alt, ME, DM, FFD, 1.f);
        ln_k<<<ME / 4, 256, 0, stream>>>(alt, enc_ln2_g + (size_t)i * DM, enc_ln2_b + (size_t)i * DM);
        { u16* t = cur; cur = alt; alt = t; }
    }
    u16* mem = cur;  // xa (even swaps)

    // ===== all 6 layers' cross-attn K/V projections in one GEMM (KVMAP) =====
    mgemm_k<0, 0, 64, 64, 0, 1><<<mg(ME, NL * 2 * DM, 64, 64), 256, 0, stream>>>(mem, dec_ca_wb, kvbias, nullptr, kvall, ME, NL * 2 * DM, DM, 1.f);

    // ===== decoder =====
    mgemm_k<0, 0, 32, 32, 2, 0><<<mg(MD, DM, 32, 32), 256, 0, stream>>>(tgt_b, dec_in_wb, dec_in_b, nullptr, ya, MD, DM, HD, SQD);

    u16* dc = ya; u16* da = yb;
    for (int i = 0; i < NL; i++) {
        // --- self-attention (causal), fused QKV ---
        const u16* W = dec_sa_wb + (size_t)i * 3 * DM * DM;
        const float* Bw = dec_sa_b + (size_t)i * 3 * DM;
        mgemm_k<0, 0, 64, 32, 0, 0><<<mg(MD, 3 * DM, 64, 32), 256, 0, stream>>>(dc, W, Bw, nullptr, reg1, MD, 3 * DM, DM, 1.f);
        flash_k<1, 32><<<dim3(TGT / 32, BH), 128, 0, stream>>>(reg1, 3 * DM, reg1 + DM, 3 * DM, reg1 + 2 * DM, 3 * DM, tbuf, TGT, TGT);
        mgemm_k<0, 0, 32, 32, 0, 0><<<mg(MD, DM, 32, 32), 256, 0, stream>>>(tbuf, dec_sao_wb + (size_t)i * DM * DM, dec_sa_out_b + (size_t)i * DM, dc, da, MD, DM, DM, 1.f);
        ln_k<<<MD / 4, 256, 0, stream>>>(da, dec_ln1_g + (size_t)i * DM, dec_ln1_b + (size_t)i * DM);
        { u16* t = dc; dc = da; da = t; }

        // --- cross-attention (K/V precomputed in kvall) ---
        const u16* Wc = dec_ca_wb + (size_t)i * 3 * DM * DM;
        const float* Bc = dec_ca_b + (size_t)i * 3 * DM;
        u16* qbuf = reg1;
        mgemm_k<0, 0, 32, 32, 0, 0><<<mg(MD, DM, 32, 32), 256, 0, stream>>>(dc, Wc, Bc, nullptr, qbuf, MD, DM, DM, 1.f);
        const u16* kvl = kvall + (size_t)i * 2 * DM;
        flash_k<0, 32><<<dim3(TGT / 32, BH), 128, 0, stream>>>(qbuf, DM, kvl, NL * 2 * DM, kvl + DM, NL * 2 * DM, tbuf, TGT, SEQ);
        mgemm_k<0, 0, 32, 32, 0, 0><<<mg(MD, DM, 32, 32), 256, 0, stream>>>(tbuf, dec_cao_wb + (size_t)i * DM * DM, dec_ca_out_b + (size_t)i * DM, dc, da, MD, DM, DM, 1.f);
        ln_k<<<MD / 4, 256, 0, stream>>>(da, dec_ln2_g + (size_t)i * DM, dec_ln2_b + (size_t)i * DM);
        { u16* t = dc; dc = da; da = t; }

        // --- feed-forward ---
        mgemm_k<1, 0, 64, 32, 0, 0><<<mg(MD, FFD, 64, 32), 256, 0, stream>>>(dc, dec_f1_wb + (size_t)i * FFD * DM, dec_ff1_b + (size_t)i * FFD, nullptr, reg1, MD, FFD, DM, 1.f);
        mgemm_k<0, 0, 32, 32, 0, 0><<<mg(MD, DM, 32, 32), 256, 0, stream>>>(reg1, dec_f2_wb + (size_t)i * DM * FFD, dec_ff2_b + (size_t)i * DM, dc, da, MD, DM, FFD, 1.f);
        ln_k<<<MD / 4, 256, 0, stream>>>(da, dec_ln3_g + (size_t)i * DM, dec_ln3_b + (size_t)i * DM);
        { u16* t = dc; dc = da; da = t; }
    }

    // ===== final projection (N=64, fp32 into d_out) =====
    mgemm_k<0, 1, 32, 32, 0, 0><<<mg(MD, HD, 32, 32), 256, 0, stream>>>(dc, out_wb, out_b, nullptr, (float*)d_out, MD, HD, DM, 1.f);
}

// Round 10
// 1210.604 us; speedup vs baseline: 1.3795x; 1.0079x over previous
//
#include <hip/hip_runtime.h>
#include <hip/hip_bf16.h>
#include <math.h>

#define BB 4
#define SEQ 512
#define TGT 256
#define DM 512
#define FFD 2048
#define NH 8
#define HD 64
#define NL 6

typedef unsigned short u16;
typedef __attribute__((ext_vector_type(4))) float f4;
typedef __attribute__((ext_vector_type(4))) unsigned short us4;
typedef __attribute__((ext_vector_type(8))) unsigned short us8;
typedef __attribute__((ext_vector_type(8))) short s8;

__device__ inline u16 f2b(float f) {
    __hip_bfloat16 h = __float2bfloat16(f);
    return *reinterpret_cast<u16*>(&h);
}
__device__ inline float b2f(u16 u) {
    unsigned int x = ((unsigned int)u) << 16;
    float f;
    __builtin_memcpy(&f, &x, 4);
    return f;
}
__device__ inline us4 cvt4(f4 v) {
    us4 u;
    u.x = f2b(v.x); u.y = f2b(v.y); u.z = f2b(v.z); u.w = f2b(v.w);
    return u;
}

// ---------------- batched fp32 -> bf16 cast ----------------
// Pinned at ~75us / 2.4 TB/s across three access-pattern variants (R0/R2/R3).
// R8 lesson: do NOT fuse the cast/LN into consumers -- consumer GEMMs re-read
// per K-step, multiplying the elementwise work by the reuse factor.
struct CastSegs {
    const float* src[24];
    u16* dst[24];
    int cum[25];   // cumulative n4 (f4 groups)
    int nseg;
};

__global__ __launch_bounds__(256) void castseg_k(CastSegs cs)
{
    const int g0 = blockIdx.x << 11;           // first f4-group of this block
    int s = 0;
    while (g0 >= cs.cum[s + 1]) s++;           // block-uniform search
    const f4* __restrict__ sp = (const f4*)cs.src[s];
    us4* __restrict__ dp = (us4*)cs.dst[s];
    const int base = g0 - cs.cum[s] + (int)threadIdx.x;

    f4 v[8];
#pragma unroll
    for (int k = 0; k < 8; k++) v[k] = sp[base + (k << 8)];
#pragma unroll
    for (int k = 0; k < 8; k++) dp[base + (k << 8)] = cvt4(v[k]);
}

// ---------------- stack decoder cross-attn KV biases: [6][1024] fp32 ----------------
__global__ void kvbias_k(const float* __restrict__ dec_ca_b, float* __restrict__ out)
{
    int idx = blockIdx.x * blockDim.x + threadIdx.x;
    if (idx >= NL * 2 * DM) return;
    int layer = idx >> 10, j = idx & 1023;
    out[idx] = dec_ca_b[layer * 3 * DM + DM + j];
}

// ============ MFMA GEMM, bf16, BMxBN tile, BK=64, double-buffered LDS ============
// PE: 0 none, 1 encoder sinusoidal pe, 2 decoder pe row 0
// KVMAP: remap B row n -> layer*3*DM + DM + (n&1023) (kvall GEMM reads the
// K/V rows of the [L][3*DM][DM] dec_ca weight stack in place).
// BN templated (R7 win): these GEMMs are latency-bound (R5: MfmaUtil 7.6% @
// occ 19%); blocks/CU + grid coverage is the operative lever (R6 +13us,
// R7 +38us). BN=32 doubles coverage for the N=512 GEMMs.
// R9 lesson: coverage-by-splitting only wins when per-block work shrinks
// proportionally (GEMM B-tile does; flash K/V staging does not).
template <int RELU, int OUTF32, int BM, int BN, int PE, int KVMAP>
__global__ __launch_bounds__(256) void mgemm_k(
    const u16* __restrict__ A, const u16* __restrict__ W,
    const float* __restrict__ bias, const u16* __restrict__ resid,
    void* __restrict__ Cv, int M, int N, int K, float alpha)
{
    constexpr int MI = BM / 32;   // 16-row fragments per wave
    constexpr int NJ = BN / 32;   // 16-col fragments per wave
    __shared__ u16 As[2][BM][72];
    __shared__ u16 Bs[2][BN][72];
    const int bm = blockIdx.y * BM, bn = blockIdx.x * BN;
    const int tid = threadIdx.x;
    const int wave = tid >> 6, lane = tid & 63;
    const int wr = (wave >> 1) * (BM / 2), wc = (wave & 1) * (BN / 2);
    const int lm = lane & 15, quad = lane >> 4;
    const int sar = (BM == 64) ? (tid >> 2) : (tid >> 3);
    const int sac = (BM == 64) ? ((tid & 3) * 16) : ((tid & 7) * 8);
    const int sbr = (BN == 64) ? (tid >> 2) : (tid >> 3);
    const int sbc = (BN == 64) ? ((tid & 3) * 16) : ((tid & 7) * 8);

    int brow = bn + sbr;
    if (KVMAP) brow = (brow >> 10) * (3 * DM) + DM + (brow & 1023);

    const u16* Arow = A + (size_t)(bm + sar) * K + sac;
    const u16* Wrow = W + (size_t)brow * K + sbc;

    us8 a0 = *(const us8*)(Arow);
    us8 a1;
    if (BM == 64) a1 = *(const us8*)(Arow + 8);
    us8 b0 = *(const us8*)(Wrow);
    us8 b1;
    if (BN == 64) b1 = *(const us8*)(Wrow + 8);

    f4 acc[MI][NJ];
#pragma unroll
    for (int i = 0; i < MI; i++)
#pragma unroll
        for (int j = 0; j < NJ; j++) acc[i][j] = (f4)(0.f);

    const int nk = K >> 6;
    *(us8*)&As[0][sar][sac] = a0;
    if (BM == 64) *(us8*)&As[0][sar][sac + 8] = a1;
    *(us8*)&Bs[0][sbr][sbc] = b0;
    if (BN == 64) *(us8*)&Bs[0][sbr][sbc + 8] = b1;
    __syncthreads();

    for (int t = 0; t < nk; t++) {
        const int cb = t & 1;
        if (t + 1 < nk) {
            int off = (t + 1) << 6;
            a0 = *(const us8*)(Arow + off);
            if (BM == 64) a1 = *(const us8*)(Arow + off + 8);
            b0 = *(const us8*)(Wrow + off);
            if (BN == 64) b1 = *(const us8*)(Wrow + off + 8);
        }
#pragma unroll
        for (int ks = 0; ks < 2; ks++) {
            s8 af[MI], bfr[NJ];
#pragma unroll
            for (int i = 0; i < MI; i++) af[i] = *(const s8*)&As[cb][wr + i * 16 + lm][ks * 32 + quad * 8];
#pragma unroll
            for (int j = 0; j < NJ; j++) bfr[j] = *(const s8*)&Bs[cb][wc + j * 16 + lm][ks * 32 + quad * 8];
#pragma unroll
            for (int i = 0; i < MI; i++)
#pragma unroll
                for (int j = 0; j < NJ; j++)
                    acc[i][j] = __builtin_amdgcn_mfma_f32_16x16x32_bf16(af[i], bfr[j], acc[i][j], 0, 0, 0);
        }
        if (t + 1 < nk) {
            const int nb = cb ^ 1;
            *(us8*)&As[nb][sar][sac] = a0;
            if (BM == 64) *(us8*)&As[nb][sar][sac + 8] = a1;
            *(us8*)&Bs[nb][sbr][sbc] = b0;
            if (BN == 64) *(us8*)&Bs[nb][sbr][sbc + 8] = b1;
            __syncthreads();
        }
    }

#pragma unroll
    for (int j = 0; j < NJ; j++) {
        int n = bn + wc + j * 16 + lm;
        float bv = bias[n];
        float dv = 0.f;
        if (PE == 1) dv = expf((float)(n & ~1) * (-9.210340371976184f / (float)DM));
#pragma unroll
        for (int i = 0; i < MI; i++) {
#pragma unroll
            for (int r = 0; r < 4; r++) {
                int m = bm + wr + i * 16 + quad * 4 + r;
                float v = (acc[i][j][r] + bv) * alpha;
                if (PE == 1) {
                    float ang = (float)(m & (SEQ - 1)) * dv;
                    v += (n & 1) ? cosf(ang) : sinf(ang);
                }
                if (PE == 2) { if (n & 1) v += 1.f; }
                if (RELU) v = fmaxf(v, 0.f);
                size_t off = (size_t)m * N + n;
                if (resid) v += b2f(resid[off]);
                if (OUTF32) ((float*)Cv)[off] = v;
                else        ((u16*)Cv)[off]  = f2b(v);
            }
        }
    }
}

// ============ Fused flash attention (verified R2/R7 structure, QBLK=64) ============
// R9 lesson: QBLK=32 decoder split was neutral-negative (K/V staging is
// per-block-constant, so 2x blocks = 2x staging work).
template <int CAUSAL>
__global__ __launch_bounds__(256) void flash_k(
    const u16* __restrict__ Q, int qs,
    const u16* __restrict__ Kp, int ks,
    const u16* __restrict__ V, int vs,
    u16* __restrict__ O, int Sq, int Sk)
{
    __shared__ u16 Qs[64][72];
    __shared__ u16 Ks[128][72];
    __shared__ u16 Vs[64][136];
    __shared__ u16 Ps[4][16][136];
    const int bm = blockIdx.x * 64;
    const int bh = blockIdx.y, b = bh >> 3, h = bh & 7;
    const int tid = threadIdx.x;
    const int wave = tid >> 6, lane = tid & 63;
    const int lm = lane & 15, quad = lane >> 4;

    const u16* Qb = Q + (size_t)(b * Sq + bm) * qs + h * HD;
    {
        int r = tid >> 2, c = (tid & 3) * 16;
        *(us8*)&Qs[r][c]     = *(const us8*)(Qb + (size_t)r * qs + c);
        *(us8*)&Qs[r][c + 8] = *(const us8*)(Qb + (size_t)r * qs + c + 8);
    }

    float mrow[4], lrow[4];
    f4 o[4];
#pragma unroll
    for (int r = 0; r < 4; r++) { mrow[r] = -1e30f; lrow[r] = 0.f; }
#pragma unroll
    for (int nt = 0; nt < 4; nt++) o[nt] = (f4)(0.f);

    const u16* Kb = Kp + (size_t)(b * Sk) * ks + h * HD;
    const u16* Vb = V + (size_t)(b * Sk) * vs + h * HD;
    int nkt = Sk >> 7;
    if (CAUSAL) { int lim = (bm + 63) / 128 + 1; if (lim < nkt) nkt = lim; }

    const int vd = tid & 63, vkb = tid >> 6;
    const int kr = tid >> 3, kc8 = (tid & 7) * 8;

    for (int kt = 0; kt < nkt; kt++) {
        const u16* Kt = Kb + ((size_t)kt << 7) * ks;
        const u16* Vt = Vb + ((size_t)kt << 7) * vs;
#pragma unroll
        for (int p = 0; p < 4; p++) {
            int r = p * 32 + kr;
            *(us8*)&Ks[r][kc8] = *(const us8*)(Kt + (size_t)r * ks + kc8);
        }
#pragma unroll
        for (int p = 0; p < 32; p++) {
            int kv = p * 4 + vkb;
            Vs[vd][kv] = Vt[(size_t)kv * vs + vd];
        }
        __syncthreads();

        f4 sa[8];
#pragma unroll
        for (int nt = 0; nt < 8; nt++) sa[nt] = (f4)(0.f);
#pragma unroll
        for (int ks2 = 0; ks2 < 2; ks2++) {
            s8 aq = *(const s8*)&Qs[wave * 16 + lm][ks2 * 32 + quad * 8];
#pragma unroll
            for (int nt = 0; nt < 8; nt++) {
                s8 bk = *(const s8*)&Ks[nt * 16 + lm][ks2 * 32 + quad * 8];
                sa[nt] = __builtin_amdgcn_mfma_f32_16x16x32_bf16(aq, bk, sa[nt], 0, 0, 0);
            }
        }
        float tmx[4] = {-1e30f, -1e30f, -1e30f, -1e30f};
#pragma unroll
        for (int nt = 0; nt < 8; nt++) {
#pragma unroll
            for (int r = 0; r < 4; r++) {
                float v = sa[nt][r] * 0.125f;
                if (CAUSAL) {
                    int col = (kt << 7) + nt * 16 + lm;
                    int row = bm + wave * 16 + quad * 4 + r;
                    if (col > row) v = -1e30f;
                }
                sa[nt][r] = v;
                tmx[r] = fmaxf(tmx[r], v);
            }
        }
#pragma unroll
        for (int st = 1; st < 16; st <<= 1)
#pragma unroll
            for (int r = 0; r < 4; r++) tmx[r] = fmaxf(tmx[r], __shfl_xor(tmx[r], st));
        float al[4];
#pragma unroll
        for (int r = 0; r < 4; r++) {
            float mn = fmaxf(mrow[r], tmx[r]);
            al[r] = __expf(mrow[r] - mn);
            mrow[r] = mn;
        }
        float ts[4] = {0.f, 0.f, 0.f, 0.f};
#pragma unroll
        for (int nt = 0; nt < 8; nt++) {
#pragma unroll
            for (int r = 0; r < 4; r++) {
                float pe = __expf(sa[nt][r] - mrow[r]);
                sa[nt][r] = pe;
                ts[r] += pe;
            }
        }
#pragma unroll
        for (int st = 1; st < 16; st <<= 1)
#pragma unroll
            for (int r = 0; r < 4; r++) ts[r] += __shfl_xor(ts[r], st);
#pragma unroll
        for (int r = 0; r < 4; r++) lrow[r] = lrow[r] * al[r] + ts[r];
#pragma unroll
        for (int nt = 0; nt < 4; nt++)
#pragma unroll
            for (int r = 0; r < 4; r++) o[nt][r] *= al[r];
#pragma unroll
        for (int nt = 0; nt < 8; nt++)
#pragma unroll
            for (int r = 0; r < 4; r++)
                Ps[wave][quad * 4 + r][nt * 16 + lm] = f2b(sa[nt][r]);
#pragma unroll
        for (int kc = 0; kc < 4; kc++) {
            s8 ap = *(const s8*)&Ps[wave][lm][kc * 32 + quad * 8];
#pragma unroll
            for (int nt = 0; nt < 4; nt++) {
                s8 bv = *(const s8*)&Vs[nt * 16 + lm][kc * 32 + quad * 8];
                o[nt] = __builtin_amdgcn_mfma_f32_16x16x32_bf16(ap, bv, o[nt], 0, 0, 0);
            }
        }
        __syncthreads();
    }

    float inv[4];
#pragma unroll
    for (int r = 0; r < 4; r++) inv[r] = 1.f / lrow[r];
#pragma unroll
    for (int nt = 0; nt < 4; nt++) {
#pragma unroll
        for (int r = 0; r < 4; r++) {
            int m = bm + wave * 16 + quad * 4 + r;
            O[(size_t)(b * Sq + m) * DM + h * HD + nt * 16 + lm] = f2b(o[nt][r] * inv[r]);
        }
    }
}

// ---------------- layernorm: 1 wave per row of 512, no barriers ----------------
__global__ __launch_bounds__(256) void ln_k(u16* __restrict__ x,
                                            const float* __restrict__ g,
                                            const float* __restrict__ b)
{
    const int wave = threadIdx.x >> 6, lane = threadIdx.x & 63;
    const int row = blockIdx.x * 4 + wave;
    u16* xr = x + (size_t)row * DM + lane * 8;
    us8 v8 = *(const us8*)xr;
    float v[8];
    float s = 0.f;
#pragma unroll
    for (int e = 0; e < 8; e++) { v[e] = b2f(v8[e]); s += v[e]; }
#pragma unroll
    for (int st = 1; st < 64; st <<= 1) s += __shfl_xor(s, st);
    float mean = s * (1.f / DM);
    float q = 0.f;
#pragma unroll
    for (int e = 0; e < 8; e++) { float d = v[e] - mean; q += d * d; }
#pragma unroll
    for (int st = 1; st < 64; st <<= 1) q += __shfl_xor(q, st);
    float rstd = rsqrtf(q * (1.f / DM) + 1e-5f);
    f4 g0 = *(const f4*)(g + lane * 8), g1 = *(const f4*)(g + lane * 8 + 4);
    f4 b0 = *(const f4*)(b + lane * 8), b1 = *(const f4*)(b + lane * 8 + 4);
    us8 o;
#pragma unroll
    for (int e = 0; e < 4; e++) {
        o[e]     = f2b((v[e]     - mean) * rstd * g0[e] + b0[e]);
        o[e + 4] = f2b((v[e + 4] - mean) * rstd * g1[e] + b1[e]);
    }
    *(us8*)xr = o;
}

// ---------------- host orchestration ----------------
static inline dim3 mg(int M, int N, int BM, int BN) { return dim3(N / BN, M / BM); }

extern "C" void kernel_launch(void* const* d_in, const int* in_sizes, int n_in,
                              void* d_out, int out_size, void* d_ws, size_t ws_size,
                              hipStream_t stream)
{
    const float* src       = (const float*)d_in[0];
    const float* tgt       = (const float*)d_in[1];
    const float* enc_in_w  = (const float*)d_in[2];
    const float* enc_in_b  = (const float*)d_in[3];
    const float* dec_in_w  = (const float*)d_in[4];
    const float* dec_in_b  = (const float*)d_in[5];
    const float* out_w     = (const float*)d_in[6];
    const float* out_b     = (const float*)d_in[7];
    const float* enc_attn_w = (const float*)d_in[8];
    const float* enc_attn_b = (const float*)d_in[9];
    const float* enc_out_w  = (const float*)d_in[10];
    const float* enc_out_b  = (const float*)d_in[11];
    const float* enc_ff1_w  = (const float*)d_in[12];
    const float* enc_ff1_b  = (const float*)d_in[13];
    const float* enc_ff2_w  = (const float*)d_in[14];
    const float* enc_ff2_b  = (const float*)d_in[15];
    const float* enc_ln1_g  = (const float*)d_in[16];
    const float* enc_ln1_b  = (const float*)d_in[17];
    const float* enc_ln2_g  = (const float*)d_in[18];
    const float* enc_ln2_b  = (const float*)d_in[19];
    const float* dec_sa_w     = (const float*)d_in[20];
    const float* dec_sa_b     = (const float*)d_in[21];
    const float* dec_sa_out_w = (const float*)d_in[22];
    const float* dec_sa_out_b = (const float*)d_in[23];
    const float* dec_ca_w     = (const float*)d_in[24];
    const float* dec_ca_b     = (const float*)d_in[25];
    const float* dec_ca_out_w = (const float*)d_in[26];
    const float* dec_ca_out_b = (const float*)d_in[27];
    const float* dec_ff1_w    = (const float*)d_in[28];
    const float* dec_ff1_b    = (const float*)d_in[29];
    const float* dec_ff2_w    = (const float*)d_in[30];
    const float* dec_ff2_b    = (const float*)d_in[31];
    const float* dec_ln1_g    = (const float*)d_in[32];
    const float* dec_ln1_b    = (const float*)d_in[33];
    const float* dec_ln2_g    = (const float*)d_in[34];
    const float* dec_ln2_b    = (const float*)d_in[35];
    const float* dec_ln3_g    = (const float*)d_in[36];
    const float* dec_ln3_b    = (const float*)d_in[37];

    const int ME = BB * SEQ;  // 2048
    const int MD = BB * TGT;  // 1024
    const int BH = BB * NH;   // 32
    const float SQD = 22.627416997969522f;  // sqrt(512)

    const size_t SZ_ATTN = (size_t)NL * 3 * DM * DM;
    const size_t SZ_OUT  = (size_t)NL * DM * DM;
    const size_t SZ_FF   = (size_t)NL * FFD * DM;

    // ---- workspace layout ----
    float* fp = (float*)d_ws;
    float* kvbias = fp; fp += NL * 2 * DM;
    u16* p = (u16*)fp;
    u16* xa   = p; p += (size_t)ME * DM;
    u16* xb   = p; p += (size_t)ME * DM;
    u16* reg1 = p; p += (size_t)ME * FFD;
    u16* tbuf = p; p += (size_t)ME * DM;
    u16* ya   = p; p += (size_t)MD * DM;
    u16* yb   = p; p += (size_t)MD * DM;
    u16* kvall = p; p += (size_t)ME * NL * 2 * DM;
    u16* src_b     = p; p += (size_t)ME * HD;
    u16* tgt_b     = p; p += (size_t)MD * HD;
    u16* enc_in_wb = p; p += (size_t)DM * HD;
    u16* dec_in_wb = p; p += (size_t)DM * HD;
    u16* out_wb    = p; p += (size_t)HD * DM;
    u16* enc_at_wb = p; p += SZ_ATTN;
    u16* enc_ow_wb = p; p += SZ_OUT;
    u16* enc_f1_wb = p; p += SZ_FF;
    u16* enc_f2_wb = p; p += SZ_FF;
    u16* dec_sa_wb = p; p += SZ_ATTN;
    u16* dec_sao_wb = p; p += SZ_OUT;
    u16* dec_ca_wb = p; p += SZ_ATTN;
    u16* dec_cao_wb = p; p += SZ_OUT;
    u16* dec_f1_wb = p; p += SZ_FF;
    u16* dec_f2_wb = p; p += SZ_FF;

    // ===== single batched cast (15 segments; KV weights read via KVMAP) =====
    CastSegs cs;
    int ns = 0;
    auto seg = [&](const float* s, u16* d, size_t n) {
        cs.src[ns] = s; cs.dst[ns] = d;
        cs.cum[ns + 1] = cs.cum[ns] + (int)(n / 4);
        ns++;
    };
    cs.cum[0] = 0;
    seg(src,          src_b,     (size_t)ME * HD);
    seg(tgt,          tgt_b,     (size_t)MD * HD);
    seg(enc_in_w,     enc_in_wb, (size_t)DM * HD);
    seg(dec_in_w,     dec_in_wb, (size_t)DM * HD);
    seg(out_w,        out_wb,    (size_t)HD * DM);
    seg(enc_attn_w,   enc_at_wb, SZ_ATTN);
    seg(enc_out_w,    enc_ow_wb, SZ_OUT);
    seg(enc_ff1_w,    enc_f1_wb, SZ_FF);
    seg(enc_ff2_w,    enc_f2_wb, SZ_FF);
    seg(dec_sa_w,     dec_sa_wb, SZ_ATTN);
    seg(dec_sa_out_w, dec_sao_wb, SZ_OUT);
    seg(dec_ca_w,     dec_ca_wb, SZ_ATTN);
    seg(dec_ca_out_w, dec_cao_wb, SZ_OUT);
    seg(dec_ff1_w,    dec_f1_wb, SZ_FF);
    seg(dec_ff2_w,    dec_f2_wb, SZ_FF);
    cs.nseg = ns;
    castseg_k<<<cs.cum[ns] >> 11, 256, 0, stream>>>(cs);
    kvbias_k<<<(NL * 2 * DM + 255) / 256, 256, 0, stream>>>(dec_ca_b, kvbias);

    // ===== encoder =====
    mgemm_k<0, 0, 64, 32, 1, 0><<<mg(ME, DM, 64, 32), 256, 0, stream>>>(src_b, enc_in_wb, enc_in_b, nullptr, xa, ME, DM, HD, SQD);

    u16* cur = xa; u16* alt = xb;
    for (int i = 0; i < NL; i++) {
        const u16* W = enc_at_wb + (size_t)i * 3 * DM * DM;
        const float* Bw = enc_attn_b + (size_t)i * 3 * DM;
        mgemm_k<0, 0, 64, 64, 0, 0><<<mg(ME, 3 * DM, 64, 64), 256, 0, stream>>>(cur, W, Bw, nullptr, reg1, ME, 3 * DM, DM, 1.f);
        flash_k<0><<<dim3(SEQ / 64, BH), 256, 0, stream>>>(reg1, 3 * DM, reg1 + DM, 3 * DM, reg1 + 2 * DM, 3 * DM, tbuf, SEQ, SEQ);
        mgemm_k<0, 0, 32, 32, 0, 0><<<mg(ME, DM, 32, 32), 256, 0, stream>>>(tbuf, enc_ow_wb + (size_t)i * DM * DM, enc_out_b + (size_t)i * DM, cur, alt, ME, DM, DM, 1.f);
        ln_k<<<ME / 4, 256, 0, stream>>>(alt, enc_ln1_g + (size_t)i * DM, enc_ln1_b + (size_t)i * DM);
        { u16* t = cur; cur = alt; alt = t; }
        mgemm_k<1, 0, 64, 64, 0, 0><<<mg(ME, FFD, 64, 64), 256, 0, stream>>>(cur, enc_f1_wb + (size_t)i * FFD * DM, enc_ff1_b + (size_t)i * FFD, nullptr, reg1, ME, FFD, DM, 1.f);
        mgemm_k<0, 0, 32, 32, 0, 0><<<mg(ME, DM, 32, 32), 256, 0, stream>>>(reg1, enc_f2_wb + (size_t)i * DM * FFD, enc_ff2_b + (size_t)i * DM, cur, alt, ME, DM, FFD, 1.f);
        ln_k<<<ME / 4, 256, 0, stream>>>(alt, enc_ln2_g + (size_t)i * DM, enc_ln2_b + (size_t)i * DM);
        { u16* t = cur; cur = alt; alt = t; }
    }
    u16* mem = cur;  // xa (even swaps)

    // ===== all 6 layers' cross-attn K/V projections in one GEMM (KVMAP) =====
    mgemm_k<0, 0, 64, 64, 0, 1><<<mg(ME, NL * 2 * DM, 64, 64), 256, 0, stream>>>(mem, dec_ca_wb, kvbias, nullptr, kvall, ME, NL * 2 * DM, DM, 1.f);

    // ===== decoder =====
    mgemm_k<0, 0, 32, 32, 2, 0><<<mg(MD, DM, 32, 32), 256, 0, stream>>>(tgt_b, dec_in_wb, dec_in_b, nullptr, ya, MD, DM, HD, SQD);

    u16* dc = ya; u16* da = yb;
    for (int i = 0; i < NL; i++) {
        // --- self-attention (causal), fused QKV ---
        const u16* W = dec_sa_wb + (size_t)i * 3 * DM * DM;
        const float* Bw = dec_sa_b + (size_t)i * 3 * DM;
        mgemm_k<0, 0, 64, 32, 0, 0><<<mg(MD, 3 * DM, 64, 32), 256, 0, stream>>>(dc, W, Bw, nullptr, reg1, MD, 3 * DM, DM, 1.f);
        flash_k<1><<<dim3(TGT / 64, BH), 256, 0, stream>>>(reg1, 3 * DM, reg1 + DM, 3 * DM, reg1 + 2 * DM, 3 * DM, tbuf, TGT, TGT);
        mgemm_k<0, 0, 32, 32, 0, 0><<<mg(MD, DM, 32, 32), 256, 0, stream>>>(tbuf, dec_sao_wb + (size_t)i * DM * DM, dec_sa_out_b + (size_t)i * DM, dc, da, MD, DM, DM, 1.f);
        ln_k<<<MD / 4, 256, 0, stream>>>(da, dec_ln1_g + (size_t)i * DM, dec_ln1_b + (size_t)i * DM);
        { u16* t = dc; dc = da; da = t; }

        // --- cross-attention (K/V precomputed in kvall) ---
        const u16* Wc = dec_ca_wb + (size_t)i * 3 * DM * DM;
        const float* Bc = dec_ca_b + (size_t)i * 3 * DM;
        u16* qbuf = reg1;
        mgemm_k<0, 0, 32, 32, 0, 0><<<mg(MD, DM, 32, 32), 256, 0, stream>>>(dc, Wc, Bc, nullptr, qbuf, MD, DM, DM, 1.f);
        const u16* kvl = kvall + (size_t)i * 2 * DM;
        flash_k<0><<<dim3(TGT / 64, BH), 256, 0, stream>>>(qbuf, DM, kvl, NL * 2 * DM, kvl + DM, NL * 2 * DM, tbuf, TGT, SEQ);
        mgemm_k<0, 0, 32, 32, 0, 0><<<mg(MD, DM, 32, 32), 256, 0, stream>>>(tbuf, dec_cao_wb + (size_t)i * DM * DM, dec_ca_out_b + (size_t)i * DM, dc, da, MD, DM, DM, 1.f);
        ln_k<<<MD / 4, 256, 0, stream>>>(da, dec_ln2_g + (size_t)i * DM, dec_ln2_b + (size_t)i * DM);
        { u16* t = dc; dc = da; da = t; }

        // --- feed-forward ---
        mgemm_k<1, 0, 64, 32, 0, 0><<<mg(MD, FFD, 64, 32), 256, 0, stream>>>(dc, dec_f1_wb + (size_t)i * FFD * DM, dec_ff1_b + (size_t)i * FFD, nullptr, reg1, MD, FFD, DM, 1.f);
        mgemm_k<0, 0, 32, 32, 0, 0><<<mg(MD, DM, 32, 32), 256, 0, stream>>>(reg1, dec_f2_wb + (size_t)i * DM * FFD, dec_ff2_b + (size_t)i * DM, dc, da, MD, DM, FFD, 1.f);
        ln_k<<<MD / 4, 256, 0, stream>>>(da, dec_ln3_g + (size_t)i * DM, dec_ln3_b + (size_t)i * DM);
        { u16* t = dc; dc = da; da = t; }
    }

    // ===== final projection (N=64, fp32 into d_out) =====
    mgemm_k<0, 1, 32, 32, 0, 0><<<mg(MD, HD, 32, 32), 256, 0, stream>>>(dc, out_wb, out_b, nullptr, (float*)d_out, MD, HD, DM, 1.f);
}